// Round 9
// baseline (875.311 us; speedup 1.0000x reference)
//
#include <hip/hip_runtime.h>
#include <stdint.h>

// Problem constants
#define BB 8
#define TT 4096
#define HH 1024
#define SS 64
#define NHH 16
#define DHH 64

typedef __attribute__((ext_vector_type(8))) short short8;
typedef __attribute__((ext_vector_type(8))) unsigned short ushortx8;
typedef __attribute__((ext_vector_type(4))) float f32x4;
typedef unsigned short u16;

#define GLOAD16(gp, lp)                                                   \
  __builtin_amdgcn_global_load_lds(                                      \
      (const __attribute__((address_space(1))) void*)(gp),               \
      (__attribute__((address_space(3))) void*)(lp), 16, 0, 0)

#define WAITVM(n)                                                         \
  asm volatile("s_waitcnt vmcnt(" #n ")" ::: "memory");                  \
  __builtin_amdgcn_sched_barrier(0)

__device__ __forceinline__ u16 f2bf(float f) {
  union { float f; uint32_t u; } v;
  v.f = f;
  uint32_t u = v.u;
  uint32_t r = u + 0x7fffu + ((u >> 16) & 1u);
  return (u16)(r >> 16);
}

__device__ __forceinline__ float bf2f(u16 b) {
  union { uint32_t u; float f; } v;
  v.u = ((uint32_t)b) << 16;
  return v.f;
}

// Stage a 128-row x 64-col f32 tile (row stride ld) into swizzled bf16 LDS.
// LDS layout: row*64 + (slot ^ (row&7))*8, slot = k/8 (8 slots of 8 bf16 = 16B).
__device__ __forceinline__ void stage_tile(u16* lds, const float* src, int ld, int tid) {
#pragma unroll
  for (int q = 0; q < 4; ++q) {
    int slot_id = tid + (q << 8);
    int row = slot_id >> 3;
    int sl = slot_id & 7;
    const float* p = src + (size_t)row * ld + (sl << 3);
    float4 x0 = *(const float4*)(p);
    float4 x1 = *(const float4*)(p + 4);
    ushortx8 o;
    o[0] = f2bf(x0.x); o[1] = f2bf(x0.y); o[2] = f2bf(x0.z); o[3] = f2bf(x0.w);
    o[4] = f2bf(x1.x); o[5] = f2bf(x1.y); o[6] = f2bf(x1.z); o[7] = f2bf(x1.w);
    *(ushortx8*)(&lds[(row << 6) + (((sl ^ (row & 7)) << 3))]) = o;
  }
}

// ---------------- conv: f32 matrix -> tiled pre-swizzled bf16 ----------------
__global__ __launch_bounds__(256) void conv_tile_kernel(const float* __restrict__ src,
                                                        int ld, int ntile_k,
                                                        u16* __restrict__ dst) {
  int bid = blockIdx.x;
  int rt = bid / ntile_k;        // row-tile (128 rows)
  int kt = bid - rt * ntile_k;   // k-tile (64 cols)
  const float* s0 = src + (size_t)rt * 128 * ld + kt * 64;
  u16* d0 = dst + (size_t)bid * 8192;
  int tid = threadIdx.x;
#pragma unroll
  for (int q = 0; q < 4; ++q) {
    int slot_id = tid + (q << 8);
    int row = slot_id >> 3;
    int sl = slot_id & 7;
    const float* p = s0 + (size_t)row * ld + (sl << 3);
    float4 x0 = *(const float4*)(p);
    float4 x1 = *(const float4*)(p + 4);
    ushortx8 o;
    o[0] = f2bf(x0.x); o[1] = f2bf(x0.y); o[2] = f2bf(x0.z); o[3] = f2bf(x0.w);
    o[4] = f2bf(x1.x); o[5] = f2bf(x1.y); o[6] = f2bf(x1.z); o[7] = f2bf(x1.w);
    *(ushortx8*)(&d0[(row << 6) + (((sl ^ (row & 7)) << 3))]) = o;
  }
}

// ---------------- K1: sentence mean pooling from tiled bf16 hbf ----------------
__global__ __launch_bounds__(256) void pool_bf_kernel(const u16* __restrict__ hbf,
                                                      const int* __restrict__ bounds,
                                                      float* __restrict__ sent) {
  int bs = blockIdx.x;           // b*64 + s
  int b = bs >> 6;
  int start = bounds[bs * 2];
  int end = bounds[bs * 2 + 1];
  int lo = max(start, 0), hi = min(end, TT);
  int cnt = max(hi - lo, 0);
  float inv = 1.0f / (float)max(cnt, 1);
  int tid = threadIdx.x;
  int sg = tid >> 1;             // 0..127 -> cols sg*8 .. sg*8+7
  int half = tid & 1;
  int kt = sg >> 3, slot = sg & 7;
  float a[8] = {};
  for (int t = lo + half; t < hi; t += 2) {
    int grow = b * TT + t;
    int rt = grow >> 7, r = grow & 127;
    const u16* tile = hbf + ((size_t)rt * 16 + kt) * 8192;
    ushortx8 v = *(const ushortx8*)(&tile[(r << 6) + ((slot ^ (r & 7)) << 3)]);
#pragma unroll
    for (int j = 0; j < 8; ++j) a[j] += bf2f(v[j]);
  }
#pragma unroll
  for (int j = 0; j < 8; ++j) a[j] += __shfl_xor(a[j], 1);
  if (half == 0) {
    float* d = sent + (size_t)bs * HH + sg * 8;
#pragma unroll
    for (int j = 0; j < 8; ++j) d[j] = a[j] * inv;
  }
}

// ---------------- setup: bias-init qkv/att/cbuf + sid + tile counters ----------------
__global__ __launch_bounds__(256) void setup_misc(const float* __restrict__ ipb,
                                                  const float* __restrict__ outb,
                                                  const float* __restrict__ b1,
                                                  const int* __restrict__ bounds,
                                                  float* __restrict__ qkv,
                                                  float* __restrict__ att,
                                                  float* __restrict__ cbuf,
                                                  int* __restrict__ sid,
                                                  int* __restrict__ cnt) {
  int idx = blockIdx.x * 256 + threadIdx.x;
  const int STR = 2048 * 256;
  for (int i = idx; i < 512 * 3072; i += STR) qkv[i] = ipb[i % 3072];
  for (int i = idx; i < 512 * 1024; i += STR) att[i] = outb[i & 1023];
  for (int i = idx; i < 512 * 1024; i += STR) cbuf[i] = b1[i & 1023];
  if (idx < 256) cnt[idx] = 0;
  if (idx < BB * TT) {
    int b = idx >> 12, t = idx & (TT - 1);
    int r = -1;
    for (int s = 0; s < SS; ++s) {
      int st = bounds[(b * SS + s) * 2], en = bounds[(b * SS + s) * 2 + 1];
      if (t >= st && t < en) { r = s; break; }
    }
    sid[idx] = r;
  }
}

// ---------------- C += A @ B^T via atomics, K-split over blockIdx.z ----------------
__global__ __launch_bounds__(256) void gemm_bt_atomic(const float* __restrict__ A, int lda,
                                                      const float* __restrict__ Bm, int ldb,
                                                      float* __restrict__ C, int ldc,
                                                      int kper) {
  __shared__ u16 As[128 * 64];
  __shared__ u16 Bs[128 * 64];
  int tid = threadIdx.x;
  int m0 = blockIdx.x * 128, n0 = blockIdx.y * 128;
  int kbeg = blockIdx.z * kper;
  f32x4 acc[4][4] = {};

  for (int k0 = kbeg; k0 < kbeg + kper; k0 += 64) {
    __syncthreads();
    stage_tile(As, A + (size_t)m0 * lda + k0, lda, tid);
    stage_tile(Bs, Bm + (size_t)n0 * ldb + k0, ldb, tid);
    __syncthreads();
    int lane = tid & 63, wid = tid >> 6;
    int wm = wid >> 1, wn = wid & 1;
    int lr = lane & 15, lg = lane >> 4;
#pragma unroll
    for (int kk = 0; kk < 2; ++kk) {
      short8 af[4], bfr[4];
#pragma unroll
      for (int i = 0; i < 4; ++i) {
        int arow = wm * 64 + i * 16 + lr;
        int aslot = (kk * 4 + lg) ^ (arow & 7);
        af[i] = *(const short8*)(&As[(arow << 6) + (aslot << 3)]);
        int brow = wn * 64 + i * 16 + lr;
        int bslot = (kk * 4 + lg) ^ (brow & 7);
        bfr[i] = *(const short8*)(&Bs[(brow << 6) + (bslot << 3)]);
      }
#pragma unroll
      for (int i = 0; i < 4; ++i)
#pragma unroll
        for (int j = 0; j < 4; ++j)
          acc[i][j] = __builtin_amdgcn_mfma_f32_16x16x32_bf16(af[i], bfr[j], acc[i][j], 0, 0, 0);
    }
  }

  int lane = tid & 63, wid = tid >> 6;
  int wm = wid >> 1, wn = wid & 1;
  int lr = lane & 15, lg = lane >> 4;
#pragma unroll
  for (int i = 0; i < 4; ++i)
#pragma unroll
    for (int j = 0; j < 4; ++j)
#pragma unroll
      for (int r = 0; r < 4; ++r) {
        int row = m0 + wm * 64 + i * 16 + lg * 4 + r;
        int col = n0 + wn * 64 + j * 16 + lr;
        atomicAdd(&C[(size_t)row * ldc + col], acc[i][j][r]);
      }
}

// ---------------- K4: attention over S=64 per (b, head) ----------------
__global__ __launch_bounds__(256) void attn_kernel(const float* __restrict__ qkv,
                                                   float* __restrict__ ctx) {
  int bh = blockIdx.x;
  int b = bh >> 4, nh = bh & 15;
  __shared__ float q[64][64], k[64][64], v[64][64], s[64][64];
  int tid = threadIdx.x;
  const float* base = qkv + (size_t)b * SS * 3072 + nh * 64;
  for (int e = tid; e < 4096; e += 256) {
    int i = e >> 6, d = e & 63;
    q[i][d] = base[(size_t)i * 3072 + d];
    k[i][d] = base[(size_t)i * 3072 + 1024 + d];
    v[i][d] = base[(size_t)i * 3072 + 2048 + d];
  }
  __syncthreads();
  for (int e = tid; e < 4096; e += 256) {
    int i = e >> 6, j = e & 63;
    float acc = 0.f;
#pragma unroll 8
    for (int d = 0; d < 64; ++d) acc += q[i][d] * k[j][d];
    s[i][j] = acc * 0.125f;  // 1/sqrt(64)
  }
  __syncthreads();
  {
    int r = tid >> 2, sub = tid & 3;
    int j0 = sub * 16;
    float m = -1e30f;
#pragma unroll
    for (int j = 0; j < 16; ++j) m = fmaxf(m, s[r][j0 + j]);
    m = fmaxf(m, __shfl_xor(m, 1));
    m = fmaxf(m, __shfl_xor(m, 2));
    float sum = 0.f;
#pragma unroll
    for (int j = 0; j < 16; ++j) {
      float e_ = __expf(s[r][j0 + j] - m);
      s[r][j0 + j] = e_;
      sum += e_;
    }
    sum += __shfl_xor(sum, 1);
    sum += __shfl_xor(sum, 2);
    float inv = 1.0f / sum;
#pragma unroll
    for (int j = 0; j < 16; ++j) s[r][j0 + j] *= inv;
  }
  __syncthreads();
  for (int e = tid; e < 4096; e += 256) {
    int i = e >> 6, d = e & 63;
    float acc = 0.f;
#pragma unroll 8
    for (int j = 0; j < 64; ++j) acc += s[i][j] * v[j][d];
    ctx[((size_t)b * SS + i) * HH + nh * 64 + d] = acc;
  }
}

// ---------------- K7: partial score, dbuf counted-vmcnt + fused output tail ----------------
// 512 threads / 8 waves (2m x 4n), XCD-grouped mapping as round 8. Double-buffered
// LDS with counted vmcnt: per step, tile i+1's 4 loads/lane stay in flight across
// both barriers (WAITVM(4), never 0 mid-loop). After spart store, blocks count up
// per M-tile; the 8th block sums the 8 partials (fixed order, deterministic) and
// writes out = h*(1+score) for its 128 rows (replaces the separate scale kernel).
__global__ __launch_bounds__(512, 4) void score_partial(const u16* __restrict__ hbf,
                                                        const u16* __restrict__ wbf,
                                                        const float* __restrict__ cbuf,
                                                        const float* __restrict__ w2,
                                                        const int* __restrict__ sid_arr,
                                                        const float* __restrict__ h,
                                                        const float* __restrict__ b2,
                                                        float* __restrict__ score_part,
                                                        int* __restrict__ cnt,
                                                        float* __restrict__ out) {
  __shared__ u16 Abuf[2][8192];
  __shared__ u16 Bbuf[2][8192];
  __shared__ float w2_lds[128];
  __shared__ int sid_lds[128];
  __shared__ float red[128];
  __shared__ int lastflag;

  int tid = threadIdx.x;
  int bid = blockIdx.x;
  int x = bid & 7;
  int g = bid >> 3;
  int mt = x * 32 + (g >> 3);
  int c = g & 7;
  int n0 = c * 128;
  size_t g0 = (size_t)mt * 128;  // global token row
  int b = (int)(g0 >> 12);       // / T
  const u16* asrc = hbf + (size_t)mt * 16 * 8192;
  const u16* bsrc = wbf + (size_t)c * 16 * 8192;

  if (tid < 128) {
    w2_lds[tid] = w2[n0 + tid];
    sid_lds[tid] = sid_arr[g0 + tid];
    red[tid] = 0.f;
  }
  // retire init loads so they never perturb the loop's vmcnt accounting
  asm volatile("s_waitcnt vmcnt(0)" ::: "memory");
  __builtin_amdgcn_sched_barrier(0);

  int lane = tid & 63, wid = tid >> 6;  // wid 0..7
  int wm = wid >> 2, wn = wid & 3;      // 2 x 4 wave grid, each 64x32
  int lr = lane & 15, lg = lane >> 4;

#define STAGE_KT(kt, bufi)                                                \
  {                                                                       \
    const u16* at_ = asrc + (kt) * 8192;                                  \
    const u16* bt_ = bsrc + (kt) * 8192;                                  \
    _Pragma("unroll")                                                     \
    for (int q = 0; q < 2; ++q) {                                         \
      int base_ = q * 4096 + wid * 512;                                   \
      GLOAD16(at_ + base_ + lane * 8, &Abuf[bufi][base_]);                \
      GLOAD16(bt_ + base_ + lane * 8, &Bbuf[bufi][base_]);                \
    }                                                                     \
  }

  STAGE_KT(0, 0);
  STAGE_KT(1, 1);

  f32x4 acc[4][2] = {};
  for (int i = 0; i < 16; ++i) {
    if (i < 15) { WAITVM(4); } else { WAITVM(0); }
    __builtin_amdgcn_s_barrier();      // tile i fully in LDS for all waves
    __builtin_amdgcn_sched_barrier(0);
    const u16* As = Abuf[i & 1];
    const u16* Bs = Bbuf[i & 1];
#pragma unroll
    for (int kk = 0; kk < 2; ++kk) {
      short8 af[4], bfr[2];
#pragma unroll
      for (int ii = 0; ii < 4; ++ii) {
        int arow = wm * 64 + ii * 16 + lr;
        int aslot = (kk * 4 + lg) ^ (arow & 7);
        af[ii] = *(const short8*)(&As[(arow << 6) + (aslot << 3)]);
      }
#pragma unroll
      for (int j = 0; j < 2; ++j) {
        int brow = wn * 32 + j * 16 + lr;
        int bslot = (kk * 4 + lg) ^ (brow & 7);
        bfr[j] = *(const short8*)(&Bs[(brow << 6) + (bslot << 3)]);
      }
#pragma unroll
      for (int ii = 0; ii < 4; ++ii)
#pragma unroll
        for (int j = 0; j < 2; ++j)
          acc[ii][j] = __builtin_amdgcn_mfma_f32_16x16x32_bf16(af[ii], bfr[j], acc[ii][j], 0, 0, 0);
    }
    __builtin_amdgcn_s_barrier();      // all waves done reading buf[i&1]
    __builtin_amdgcn_sched_barrier(0);
    if (i < 14) STAGE_KT(i + 2, i & 1);
  }
#undef STAGE_KT

  // score epilogue: sp = sum_j w2[j] * relu(u + c[sid, j]) over this wave's 32 cols
  float sp[4][4];
#pragma unroll
  for (int i = 0; i < 4; ++i) {
#pragma unroll
    for (int r = 0; r < 4; ++r) {
      int rowl = wm * 64 + i * 16 + lg * 4 + r;
      int s = sid_lds[rowl];
      int sc = s < 0 ? 0 : s;
      const float* crow = cbuf + ((size_t)b * SS + sc) * HH + n0;
      float accs = 0.f;
#pragma unroll
      for (int j = 0; j < 2; ++j) {
        int coll = wn * 32 + j * 16 + lr;
        float t = acc[i][j][r] + crow[coll];
        if (t > 0.f) accs += t * w2_lds[coll];
      }
      sp[i][r] = accs;
    }
  }

#pragma unroll
  for (int i = 0; i < 4; ++i)
#pragma unroll
    for (int r = 0; r < 4; ++r) {
      float v = sp[i][r];
      v += __shfl_xor(v, 1);
      v += __shfl_xor(v, 2);
      v += __shfl_xor(v, 4);
      v += __shfl_xor(v, 8);
      sp[i][r] = v;
    }
  if (lr == 0) {
#pragma unroll
    for (int i = 0; i < 4; ++i)
#pragma unroll
      for (int r = 0; r < 4; ++r)
        atomicAdd(&red[wm * 64 + i * 16 + lg * 4 + r], sp[i][r]);
  }
  __syncthreads();
  if (tid < 128) score_part[(size_t)c * (BB * TT) + g0 + tid] = red[tid];
  __threadfence();                     // release own spart stores to device scope
  __syncthreads();                     // all stores+fences precede the atomic
  if (tid == 0) lastflag = (atomicAdd(&cnt[mt], 1) == 7);
  __syncthreads();
  if (lastflag) {
    __threadfence();                   // acquire: see partners' spart
    if (tid < 128) {
      float s = b2[0];
#pragma unroll
      for (int cc = 0; cc < 8; ++cc) s += score_part[(size_t)cc * (BB * TT) + g0 + tid];
      red[tid] = (sid_lds[tid] >= 0) ? (1.0f + s) : 1.0f;
    }
    __syncthreads();
    const float4* h4 = (const float4*)h + g0 * 256;
    float4* o4 = (float4*)out + g0 * 256;
    for (int e = tid; e < 128 * 256; e += 512) {
      float f = red[e >> 8];
      float4 v = h4[e];
      v.x *= f; v.y *= f; v.z *= f; v.w *= f;
      o4[e] = v;
    }
  }
}

extern "C" void kernel_launch(void* const* d_in, const int* in_sizes, int n_in,
                              void* d_out, int out_size, void* d_ws, size_t ws_size,
                              hipStream_t stream) {
  const float* h        = (const float*)d_in[0];
  const int*   bounds   = (const int*)d_in[1];
  const float* in_proj_w = (const float*)d_in[2];
  const float* in_proj_b = (const float*)d_in[3];
  const float* out_w    = (const float*)d_in[4];
  const float* out_b    = (const float*)d_in[5];
  const float* w1       = (const float*)d_in[6];
  const float* b1       = (const float*)d_in[7];
  const float* w2       = (const float*)d_in[8];
  const float* b2       = (const float*)d_in[9];
  float* out = (float*)d_out;

  char* ws = (char*)d_ws;
  float* sent  = (float*)(ws);                        // 2 MB
  float* qkv   = (float*)(ws + (2ull << 20));         // 6 MB
  float* ctx   = (float*)(ws + (8ull << 20));         // 2 MB
  float* att   = (float*)(ws + (10ull << 20));        // 2 MB
  float* cbuf  = (float*)(ws + (12ull << 20));        // 2 MB
  int*   sid   = (int*)(ws + (14ull << 20));          // 128 KB
  int*   cnt   = (int*)(ws + (14ull << 20) + (512 << 10));  // 1 KB
  float* spart = (float*)(ws + (15ull << 20));        // 1 MB
  u16*   hbf   = (u16*)(ws + (16ull << 20));          // 64 MB
  u16*   wbf   = (u16*)(ws + (80ull << 20));          // 2 MB

  // pre-convert operands of the big GEMM to tiled/swizzled bf16
  conv_tile_kernel<<<256 * 16, 256, 0, stream>>>(h, HH, 16, hbf);
  conv_tile_kernel<<<8 * 16, 256, 0, stream>>>(w1, 2 * HH, 16, wbf);  // w1a: k<1024

  pool_bf_kernel<<<BB * SS, 256, 0, stream>>>(hbf, bounds, sent);
  setup_misc<<<2048, 256, 0, stream>>>(in_proj_b, out_b, b1, bounds, qkv, att, cbuf, sid, cnt);

  // qkv = sent @ in_proj_w^T + in_proj_b   (512 x 3072, K=1024), K-split x4
  gemm_bt_atomic<<<dim3(4, 24, 4), 256, 0, stream>>>(sent, HH, in_proj_w, HH, qkv, 3 * HH, 256);
  attn_kernel<<<BB * NHH, 256, 0, stream>>>(qkv, ctx);
  // attended = ctx @ out_w^T + out_b       (512 x 1024, K=1024), K-split x4
  gemm_bt_atomic<<<dim3(4, 8, 4), 256, 0, stream>>>(ctx, HH, out_w, HH, att, HH, 256);
  // c = attended @ w1b^T + b1              (512 x 1024, K=1024), w1b = w1[:, H:]
  gemm_bt_atomic<<<dim3(4, 8, 4), 256, 0, stream>>>(att, HH, w1 + HH, 2 * HH, cbuf, HH, 256);

  // big GEMM partial scores + fused output tail: 2048 blocks, XCD-grouped
  score_partial<<<2048, 512, 0, stream>>>(hbf, wbf, cbuf, w2, sid, h, b2, spart, cnt, out);
}

// Round 10
// 317.710 us; speedup vs baseline: 2.7551x; 2.7551x over previous
//
#include <hip/hip_runtime.h>
#include <stdint.h>

// Problem constants
#define BB 8
#define TT 4096
#define HH 1024
#define SS 64
#define NHH 16
#define DHH 64

typedef __attribute__((ext_vector_type(8))) short short8;
typedef __attribute__((ext_vector_type(8))) unsigned short ushortx8;
typedef __attribute__((ext_vector_type(4))) float f32x4;
typedef unsigned short u16;

#define GLOAD16(gp, lp)                                                   \
  __builtin_amdgcn_global_load_lds(                                      \
      (const __attribute__((address_space(1))) void*)(gp),               \
      (__attribute__((address_space(3))) void*)(lp), 16, 0, 0)

__device__ __forceinline__ u16 f2bf(float f) {
  union { float f; uint32_t u; } v;
  v.f = f;
  uint32_t u = v.u;
  uint32_t r = u + 0x7fffu + ((u >> 16) & 1u);
  return (u16)(r >> 16);
}

__device__ __forceinline__ float bf2f(u16 b) {
  union { uint32_t u; float f; } v;
  v.u = ((uint32_t)b) << 16;
  return v.f;
}

// Stage a 128-row x 64-col f32 tile (row stride ld) into swizzled bf16 LDS.
// LDS layout: row*64 + (slot ^ (row&7))*8, slot = k/8 (8 slots of 8 bf16 = 16B).
__device__ __forceinline__ void stage_tile(u16* lds, const float* src, int ld, int tid) {
#pragma unroll
  for (int q = 0; q < 4; ++q) {
    int slot_id = tid + (q << 8);
    int row = slot_id >> 3;
    int sl = slot_id & 7;
    const float* p = src + (size_t)row * ld + (sl << 3);
    float4 x0 = *(const float4*)(p);
    float4 x1 = *(const float4*)(p + 4);
    ushortx8 o;
    o[0] = f2bf(x0.x); o[1] = f2bf(x0.y); o[2] = f2bf(x0.z); o[3] = f2bf(x0.w);
    o[4] = f2bf(x1.x); o[5] = f2bf(x1.y); o[6] = f2bf(x1.z); o[7] = f2bf(x1.w);
    *(ushortx8*)(&lds[(row << 6) + (((sl ^ (row & 7)) << 3))]) = o;
  }
}

// ---------------- conv: f32 matrix -> tiled pre-swizzled bf16 ----------------
__global__ __launch_bounds__(256) void conv_tile_kernel(const float* __restrict__ src,
                                                        int ld, int ntile_k,
                                                        u16* __restrict__ dst) {
  int bid = blockIdx.x;
  int rt = bid / ntile_k;        // row-tile (128 rows)
  int kt = bid - rt * ntile_k;   // k-tile (64 cols)
  const float* s0 = src + (size_t)rt * 128 * ld + kt * 64;
  u16* d0 = dst + (size_t)bid * 8192;
  int tid = threadIdx.x;
#pragma unroll
  for (int q = 0; q < 4; ++q) {
    int slot_id = tid + (q << 8);
    int row = slot_id >> 3;
    int sl = slot_id & 7;
    const float* p = s0 + (size_t)row * ld + (sl << 3);
    float4 x0 = *(const float4*)(p);
    float4 x1 = *(const float4*)(p + 4);
    ushortx8 o;
    o[0] = f2bf(x0.x); o[1] = f2bf(x0.y); o[2] = f2bf(x0.z); o[3] = f2bf(x0.w);
    o[4] = f2bf(x1.x); o[5] = f2bf(x1.y); o[6] = f2bf(x1.z); o[7] = f2bf(x1.w);
    *(ushortx8*)(&d0[(row << 6) + (((sl ^ (row & 7)) << 3))]) = o;
  }
}

// ---------------- K1: sentence mean pooling from tiled bf16 hbf ----------------
__global__ __launch_bounds__(256) void pool_bf_kernel(const u16* __restrict__ hbf,
                                                      const int* __restrict__ bounds,
                                                      float* __restrict__ sent) {
  int bs = blockIdx.x;           // b*64 + s
  int b = bs >> 6;
  int start = bounds[bs * 2];
  int end = bounds[bs * 2 + 1];
  int lo = max(start, 0), hi = min(end, TT);
  int cnt = max(hi - lo, 0);
  float inv = 1.0f / (float)max(cnt, 1);
  int tid = threadIdx.x;
  int sg = tid >> 1;             // 0..127 -> cols sg*8 .. sg*8+7
  int half = tid & 1;
  int kt = sg >> 3, slot = sg & 7;
  float a[8] = {};
  for (int t = lo + half; t < hi; t += 2) {
    int grow = b * TT + t;
    int rt = grow >> 7, r = grow & 127;
    const u16* tile = hbf + ((size_t)rt * 16 + kt) * 8192;
    ushortx8 v = *(const ushortx8*)(&tile[(r << 6) + ((slot ^ (r & 7)) << 3)]);
#pragma unroll
    for (int j = 0; j < 8; ++j) a[j] += bf2f(v[j]);
  }
#pragma unroll
  for (int j = 0; j < 8; ++j) a[j] += __shfl_xor(a[j], 1);
  if (half == 0) {
    float* d = sent + (size_t)bs * HH + sg * 8;
#pragma unroll
    for (int j = 0; j < 8; ++j) d[j] = a[j] * inv;
  }
}

// ---------------- setup: bias-init qkv/att/cbuf + sid, one grid-stride kernel ----------------
__global__ __launch_bounds__(256) void setup_misc(const float* __restrict__ ipb,
                                                  const float* __restrict__ outb,
                                                  const float* __restrict__ b1,
                                                  const int* __restrict__ bounds,
                                                  float* __restrict__ qkv,
                                                  float* __restrict__ att,
                                                  float* __restrict__ cbuf,
                                                  int* __restrict__ sid) {
  int idx = blockIdx.x * 256 + threadIdx.x;
  const int STR = 2048 * 256;
  for (int i = idx; i < 512 * 3072; i += STR) qkv[i] = ipb[i % 3072];
  for (int i = idx; i < 512 * 1024; i += STR) att[i] = outb[i & 1023];
  for (int i = idx; i < 512 * 1024; i += STR) cbuf[i] = b1[i & 1023];
  if (idx < BB * TT) {
    int b = idx >> 12, t = idx & (TT - 1);
    int r = -1;
    for (int s = 0; s < SS; ++s) {
      int st = bounds[(b * SS + s) * 2], en = bounds[(b * SS + s) * 2 + 1];
      if (t >= st && t < en) { r = s; break; }
    }
    sid[idx] = r;
  }
}

// ---------------- C += A @ B^T via atomics, K-split over blockIdx.z ----------------
__global__ __launch_bounds__(256) void gemm_bt_atomic(const float* __restrict__ A, int lda,
                                                      const float* __restrict__ Bm, int ldb,
                                                      float* __restrict__ C, int ldc,
                                                      int kper) {
  __shared__ u16 As[128 * 64];
  __shared__ u16 Bs[128 * 64];
  int tid = threadIdx.x;
  int m0 = blockIdx.x * 128, n0 = blockIdx.y * 128;
  int kbeg = blockIdx.z * kper;
  f32x4 acc[4][4] = {};

  for (int k0 = kbeg; k0 < kbeg + kper; k0 += 64) {
    __syncthreads();
    stage_tile(As, A + (size_t)m0 * lda + k0, lda, tid);
    stage_tile(Bs, Bm + (size_t)n0 * ldb + k0, ldb, tid);
    __syncthreads();
    int lane = tid & 63, wid = tid >> 6;
    int wm = wid >> 1, wn = wid & 1;
    int lr = lane & 15, lg = lane >> 4;
#pragma unroll
    for (int kk = 0; kk < 2; ++kk) {
      short8 af[4], bfr[4];
#pragma unroll
      for (int i = 0; i < 4; ++i) {
        int arow = wm * 64 + i * 16 + lr;
        int aslot = (kk * 4 + lg) ^ (arow & 7);
        af[i] = *(const short8*)(&As[(arow << 6) + (aslot << 3)]);
        int brow = wn * 64 + i * 16 + lr;
        int bslot = (kk * 4 + lg) ^ (brow & 7);
        bfr[i] = *(const short8*)(&Bs[(brow << 6) + (bslot << 3)]);
      }
#pragma unroll
      for (int i = 0; i < 4; ++i)
#pragma unroll
        for (int j = 0; j < 4; ++j)
          acc[i][j] = __builtin_amdgcn_mfma_f32_16x16x32_bf16(af[i], bfr[j], acc[i][j], 0, 0, 0);
    }
  }

  int lane = tid & 63, wid = tid >> 6;
  int wm = wid >> 1, wn = wid & 1;
  int lr = lane & 15, lg = lane >> 4;
#pragma unroll
  for (int i = 0; i < 4; ++i)
#pragma unroll
    for (int j = 0; j < 4; ++j)
#pragma unroll
      for (int r = 0; r < 4; ++r) {
        int row = m0 + wm * 64 + i * 16 + lg * 4 + r;
        int col = n0 + wn * 64 + j * 16 + lr;
        atomicAdd(&C[(size_t)row * ldc + col], acc[i][j][r]);
      }
}

// ---------------- K4: attention over S=64 per (b, head) ----------------
__global__ __launch_bounds__(256) void attn_kernel(const float* __restrict__ qkv,
                                                   float* __restrict__ ctx) {
  int bh = blockIdx.x;
  int b = bh >> 4, nh = bh & 15;
  __shared__ float q[64][64], k[64][64], v[64][64], s[64][64];
  int tid = threadIdx.x;
  const float* base = qkv + (size_t)b * SS * 3072 + nh * 64;
  for (int e = tid; e < 4096; e += 256) {
    int i = e >> 6, d = e & 63;
    q[i][d] = base[(size_t)i * 3072 + d];
    k[i][d] = base[(size_t)i * 3072 + 1024 + d];
    v[i][d] = base[(size_t)i * 3072 + 2048 + d];
  }
  __syncthreads();
  for (int e = tid; e < 4096; e += 256) {
    int i = e >> 6, j = e & 63;
    float acc = 0.f;
#pragma unroll 8
    for (int d = 0; d < 64; ++d) acc += q[i][d] * k[j][d];
    s[i][j] = acc * 0.125f;  // 1/sqrt(64)
  }
  __syncthreads();
  {
    int r = tid >> 2, sub = tid & 3;
    int j0 = sub * 16;
    float m = -1e30f;
#pragma unroll
    for (int j = 0; j < 16; ++j) m = fmaxf(m, s[r][j0 + j]);
    m = fmaxf(m, __shfl_xor(m, 1));
    m = fmaxf(m, __shfl_xor(m, 2));
    float sum = 0.f;
#pragma unroll
    for (int j = 0; j < 16; ++j) {
      float e_ = __expf(s[r][j0 + j] - m);
      s[r][j0 + j] = e_;
      sum += e_;
    }
    sum += __shfl_xor(sum, 1);
    sum += __shfl_xor(sum, 2);
    float inv = 1.0f / sum;
#pragma unroll
    for (int j = 0; j < 16; ++j) s[r][j0 + j] *= inv;
  }
  __syncthreads();
  for (int e = tid; e < 4096; e += 256) {
    int i = e >> 6, d = e & 63;
    float acc = 0.f;
#pragma unroll 8
    for (int j = 0; j < 64; ++j) acc += s[i][j] * v[j][d];
    ctx[((size_t)b * SS + i) * HH + nh * 64 + d] = acc;
  }
}

// ---------------- K7: partial score, 512 threads / 8 waves (2m x 4n) ----------------
// Round-8 proven structure: single-buffer two-barrier loop, gload_lds staging,
// XCD-grouped mapping, 8 waves -> ~58% occupancy. NO device-scope fences here
// (round 9: fences invalidated per-XCD L2 -> 8x regression).
__global__ __launch_bounds__(512, 6) void score_partial(const u16* __restrict__ hbf,
                                                        const u16* __restrict__ wbf,
                                                        const float* __restrict__ cbuf,
                                                        const float* __restrict__ w2,
                                                        const int* __restrict__ sid_arr,
                                                        float* __restrict__ score_part) {
  __shared__ u16 As[8192];
  __shared__ u16 Bs[8192];
  __shared__ float w2_lds[128];
  __shared__ int sid_lds[128];
  __shared__ float red[128];

  int tid = threadIdx.x;
  int bid = blockIdx.x;
  int x = bid & 7;
  int g = bid >> 3;
  int mt = x * 32 + (g >> 3);
  int c = g & 7;
  int n0 = c * 128;
  size_t g0 = (size_t)mt * 128;  // global token row
  int b = (int)(g0 >> 12);       // / T
  const u16* asrc = hbf + (size_t)mt * 16 * 8192;
  const u16* bsrc = wbf + (size_t)c * 16 * 8192;

  if (tid < 128) {
    w2_lds[tid] = w2[n0 + tid];
    sid_lds[tid] = sid_arr[g0 + tid];
    red[tid] = 0.f;
  }

  int lane = tid & 63, wid = tid >> 6;  // wid 0..7
  int wm = wid >> 2, wn = wid & 3;      // 2 x 4 wave grid, each 64x32
  int lr = lane & 15, lg = lane >> 4;

  f32x4 acc[4][2] = {};
  for (int kt = 0; kt < 16; ++kt) {
    __syncthreads();  // previous iteration's LDS reads complete
    const u16* at = asrc + kt * 8192;
    const u16* bt = bsrc + kt * 8192;
#pragma unroll
    for (int q = 0; q < 2; ++q) {
      int base = q * 4096 + wid * 512;  // wave-uniform u16 base
      GLOAD16(at + base + lane * 8, &As[base]);
      GLOAD16(bt + base + lane * 8, &Bs[base]);
    }
    __syncthreads();  // compiler drains vmcnt(0) before barrier -> tile ready
#pragma unroll
    for (int kk = 0; kk < 2; ++kk) {
      short8 af[4], bfr[2];
#pragma unroll
      for (int i = 0; i < 4; ++i) {
        int arow = wm * 64 + i * 16 + lr;
        int aslot = (kk * 4 + lg) ^ (arow & 7);
        af[i] = *(const short8*)(&As[(arow << 6) + (aslot << 3)]);
      }
#pragma unroll
      for (int j = 0; j < 2; ++j) {
        int brow = wn * 32 + j * 16 + lr;
        int bslot = (kk * 4 + lg) ^ (brow & 7);
        bfr[j] = *(const short8*)(&Bs[(brow << 6) + (bslot << 3)]);
      }
#pragma unroll
      for (int i = 0; i < 4; ++i)
#pragma unroll
        for (int j = 0; j < 2; ++j)
          acc[i][j] = __builtin_amdgcn_mfma_f32_16x16x32_bf16(af[i], bfr[j], acc[i][j], 0, 0, 0);
    }
  }

  // score epilogue: sp = sum_j w2[j] * relu(u + c[sid, j]) over this wave's 32 cols
  float sp[4][4];
#pragma unroll
  for (int i = 0; i < 4; ++i) {
#pragma unroll
    for (int r = 0; r < 4; ++r) {
      int rowl = wm * 64 + i * 16 + lg * 4 + r;
      int s = sid_lds[rowl];
      int sc = s < 0 ? 0 : s;
      const float* crow = cbuf + ((size_t)b * SS + sc) * HH + n0;
      float accs = 0.f;
#pragma unroll
      for (int j = 0; j < 2; ++j) {
        int coll = wn * 32 + j * 16 + lr;
        float t = acc[i][j][r] + crow[coll];
        if (t > 0.f) accs += t * w2_lds[coll];
      }
      sp[i][r] = accs;
    }
  }

  // reduce across the 16 lanes of each lane-group
#pragma unroll
  for (int i = 0; i < 4; ++i)
#pragma unroll
    for (int r = 0; r < 4; ++r) {
      float v = sp[i][r];
      v += __shfl_xor(v, 1);
      v += __shfl_xor(v, 2);
      v += __shfl_xor(v, 4);
      v += __shfl_xor(v, 8);
      sp[i][r] = v;
    }
  if (lr == 0) {
#pragma unroll
    for (int i = 0; i < 4; ++i)
#pragma unroll
      for (int r = 0; r < 4; ++r)
        atomicAdd(&red[wm * 64 + i * 16 + lg * 4 + r], sp[i][r]);
  }
  __syncthreads();
  if (tid < 128) score_part[(size_t)c * (BB * TT) + g0 + tid] = red[tid];
}

// ---------------- K9: out = hbf * (1 + covered*(sum_c spart + b2)), bf16 source ----------------
__global__ __launch_bounds__(256) void scale_kernel(const u16* __restrict__ hbf,
                                                    const float* __restrict__ score_part,
                                                    const float* __restrict__ b2,
                                                    const int* __restrict__ sid_arr,
                                                    float* __restrict__ out) {
  __shared__ float fac[16];
  int tid = threadIdx.x;
  int r0 = blockIdx.x * 16;
  if (tid < 16) {
    int t = r0 + tid;
    float s = b2[0];
#pragma unroll
    for (int c = 0; c < 8; ++c) s += score_part[(size_t)c * (BB * TT) + t];
    fac[tid] = (sid_arr[t] >= 0) ? (1.0f + s) : 1.0f;
  }
  __syncthreads();
  // 16 rows * 128 ushortx8-groups = 2048 groups; 8 per thread
  for (int e = tid; e < 16 * 128; e += 256) {
    int row = e >> 7, grp = e & 127;
    int kt = grp >> 3, slot = grp & 7;
    int grow = r0 + row;
    int rt = grow >> 7, r = grow & 127;
    const u16* tile = hbf + ((size_t)rt * 16 + kt) * 8192;
    ushortx8 v = *(const ushortx8*)(&tile[(r << 6) + ((slot ^ (r & 7)) << 3)]);
    float f = fac[row];
    float4 o0, o1;
    o0.x = bf2f(v[0]) * f; o0.y = bf2f(v[1]) * f; o0.z = bf2f(v[2]) * f; o0.w = bf2f(v[3]) * f;
    o1.x = bf2f(v[4]) * f; o1.y = bf2f(v[5]) * f; o1.z = bf2f(v[6]) * f; o1.w = bf2f(v[7]) * f;
    float4* dst = (float4*)(out + (size_t)grow * HH + grp * 8);
    dst[0] = o0;
    dst[1] = o1;
  }
}

extern "C" void kernel_launch(void* const* d_in, const int* in_sizes, int n_in,
                              void* d_out, int out_size, void* d_ws, size_t ws_size,
                              hipStream_t stream) {
  const float* h        = (const float*)d_in[0];
  const int*   bounds   = (const int*)d_in[1];
  const float* in_proj_w = (const float*)d_in[2];
  const float* in_proj_b = (const float*)d_in[3];
  const float* out_w    = (const float*)d_in[4];
  const float* out_b    = (const float*)d_in[5];
  const float* w1       = (const float*)d_in[6];
  const float* b1       = (const float*)d_in[7];
  const float* w2       = (const float*)d_in[8];
  const float* b2       = (const float*)d_in[9];
  float* out = (float*)d_out;

  char* ws = (char*)d_ws;
  float* sent  = (float*)(ws);                        // 2 MB
  float* qkv   = (float*)(ws + (2ull << 20));         // 6 MB
  float* ctx   = (float*)(ws + (8ull << 20));         // 2 MB
  float* att   = (float*)(ws + (10ull << 20));        // 2 MB
  float* cbuf  = (float*)(ws + (12ull << 20));        // 2 MB
  int*   sid   = (int*)(ws + (14ull << 20));          // 128 KB
  float* spart = (float*)(ws + (15ull << 20));        // 1 MB
  u16*   hbf   = (u16*)(ws + (16ull << 20));          // 64 MB
  u16*   wbf   = (u16*)(ws + (80ull << 20));          // 2 MB

  // pre-convert operands of the big GEMM to tiled/swizzled bf16
  conv_tile_kernel<<<256 * 16, 256, 0, stream>>>(h, HH, 16, hbf);
  conv_tile_kernel<<<8 * 16, 256, 0, stream>>>(w1, 2 * HH, 16, wbf);  // w1a: k<1024

  pool_bf_kernel<<<BB * SS, 256, 0, stream>>>(hbf, bounds, sent);
  setup_misc<<<2048, 256, 0, stream>>>(in_proj_b, out_b, b1, bounds, qkv, att, cbuf, sid);

  // qkv = sent @ in_proj_w^T + in_proj_b   (512 x 3072, K=1024), K-split x8
  gemm_bt_atomic<<<dim3(4, 24, 8), 256, 0, stream>>>(sent, HH, in_proj_w, HH, qkv, 3 * HH, 128);
  attn_kernel<<<BB * NHH, 256, 0, stream>>>(qkv, ctx);
  // attended = ctx @ out_w^T + out_b       (512 x 1024, K=1024), K-split x8
  gemm_bt_atomic<<<dim3(4, 8, 8), 256, 0, stream>>>(ctx, HH, out_w, HH, att, HH, 128);
  // c = attended @ w1b^T + b1              (512 x 1024, K=1024), w1b = w1[:, H:]
  gemm_bt_atomic<<<dim3(4, 8, 8), 256, 0, stream>>>(att, HH, w1 + HH, 2 * HH, cbuf, HH, 128);

  // big GEMM partial scores: 2048 blocks, XCD-grouped, 8-wave blocks
  score_partial<<<2048, 512, 0, stream>>>(hbf, wbf, cbuf, w2, sid, spart);
  scale_kernel<<<2048, 256, 0, stream>>>(hbf, spart, b2, sid, out);
}

// Round 11
// 288.745 us; speedup vs baseline: 3.0314x; 1.1003x over previous
//
#include <hip/hip_runtime.h>
#include <stdint.h>

// Problem constants
#define BB 8
#define TT 4096
#define HH 1024
#define SS 64
#define NHH 16
#define DHH 64

typedef __attribute__((ext_vector_type(8))) short short8;
typedef __attribute__((ext_vector_type(8))) unsigned short ushortx8;
typedef __attribute__((ext_vector_type(4))) float f32x4;
typedef unsigned short u16;

#define GLOAD16(gp, lp)                                                   \
  __builtin_amdgcn_global_load_lds(                                      \
      (const __attribute__((address_space(1))) void*)(gp),               \
      (__attribute__((address_space(3))) void*)(lp), 16, 0, 0)

__device__ __forceinline__ u16 f2bf(float f) {
  union { float f; uint32_t u; } v;
  v.f = f;
  uint32_t u = v.u;
  uint32_t r = u + 0x7fffu + ((u >> 16) & 1u);
  return (u16)(r >> 16);
}

__device__ __forceinline__ float bf2f(u16 b) {
  union { uint32_t u; float f; } v;
  v.u = ((uint32_t)b) << 16;
  return v.f;
}

// Stage a 128-row x 64-col f32 tile (row stride ld) into swizzled bf16 LDS.
// LDS layout: row*64 + (slot ^ (row&7))*8, slot = k/8 (8 slots of 8 bf16 = 16B).
__device__ __forceinline__ void stage_tile(u16* lds, const float* src, int ld, int tid) {
#pragma unroll
  for (int q = 0; q < 4; ++q) {
    int slot_id = tid + (q << 8);
    int row = slot_id >> 3;
    int sl = slot_id & 7;
    const float* p = src + (size_t)row * ld + (sl << 3);
    float4 x0 = *(const float4*)(p);
    float4 x1 = *(const float4*)(p + 4);
    ushortx8 o;
    o[0] = f2bf(x0.x); o[1] = f2bf(x0.y); o[2] = f2bf(x0.z); o[3] = f2bf(x0.w);
    o[4] = f2bf(x1.x); o[5] = f2bf(x1.y); o[6] = f2bf(x1.z); o[7] = f2bf(x1.w);
    *(ushortx8*)(&lds[(row << 6) + (((sl ^ (row & 7)) << 3))]) = o;
  }
}

// ---------------- conv: f32 matrix -> tiled pre-swizzled bf16 ----------------
__global__ __launch_bounds__(256) void conv_tile_kernel(const float* __restrict__ src,
                                                        int ld, int ntile_k,
                                                        u16* __restrict__ dst) {
  int bid = blockIdx.x;
  int rt = bid / ntile_k;        // row-tile (128 rows)
  int kt = bid - rt * ntile_k;   // k-tile (64 cols)
  const float* s0 = src + (size_t)rt * 128 * ld + kt * 64;
  u16* d0 = dst + (size_t)bid * 8192;
  int tid = threadIdx.x;
#pragma unroll
  for (int q = 0; q < 4; ++q) {
    int slot_id = tid + (q << 8);
    int row = slot_id >> 3;
    int sl = slot_id & 7;
    const float* p = s0 + (size_t)row * ld + (sl << 3);
    float4 x0 = *(const float4*)(p);
    float4 x1 = *(const float4*)(p + 4);
    ushortx8 o;
    o[0] = f2bf(x0.x); o[1] = f2bf(x0.y); o[2] = f2bf(x0.z); o[3] = f2bf(x0.w);
    o[4] = f2bf(x1.x); o[5] = f2bf(x1.y); o[6] = f2bf(x1.z); o[7] = f2bf(x1.w);
    *(ushortx8*)(&d0[(row << 6) + (((sl ^ (row & 7)) << 3))]) = o;
  }
}

// ---------------- K1: sentence mean pooling from tiled bf16 hbf ----------------
__global__ __launch_bounds__(256) void pool_bf_kernel(const u16* __restrict__ hbf,
                                                      const int* __restrict__ bounds,
                                                      float* __restrict__ sent) {
  int bs = blockIdx.x;           // b*64 + s
  int b = bs >> 6;
  int start = bounds[bs * 2];
  int end = bounds[bs * 2 + 1];
  int lo = max(start, 0), hi = min(end, TT);
  int cnt = max(hi - lo, 0);
  float inv = 1.0f / (float)max(cnt, 1);
  int tid = threadIdx.x;
  int sg = tid >> 1;             // 0..127 -> cols sg*8 .. sg*8+7
  int half = tid & 1;
  int kt = sg >> 3, slot = sg & 7;
  float a[8] = {};
  for (int t = lo + half; t < hi; t += 2) {
    int grow = b * TT + t;
    int rt = grow >> 7, r = grow & 127;
    const u16* tile = hbf + ((size_t)rt * 16 + kt) * 8192;
    ushortx8 v = *(const ushortx8*)(&tile[(r << 6) + ((slot ^ (r & 7)) << 3)]);
#pragma unroll
    for (int j = 0; j < 8; ++j) a[j] += bf2f(v[j]);
  }
#pragma unroll
  for (int j = 0; j < 8; ++j) a[j] += __shfl_xor(a[j], 1);
  if (half == 0) {
    float* d = sent + (size_t)bs * HH + sg * 8;
#pragma unroll
    for (int j = 0; j < 8; ++j) d[j] = a[j] * inv;
  }
}

// ---------------- setup: bias-init qkv/att/cbuf + sid, one grid-stride kernel ----------------
__global__ __launch_bounds__(256) void setup_misc(const float* __restrict__ ipb,
                                                  const float* __restrict__ outb,
                                                  const float* __restrict__ b1,
                                                  const int* __restrict__ bounds,
                                                  float* __restrict__ qkv,
                                                  float* __restrict__ att,
                                                  float* __restrict__ cbuf,
                                                  int* __restrict__ sid) {
  int idx = blockIdx.x * 256 + threadIdx.x;
  const int STR = 2048 * 256;
  for (int i = idx; i < 512 * 3072; i += STR) qkv[i] = ipb[i % 3072];
  for (int i = idx; i < 512 * 1024; i += STR) att[i] = outb[i & 1023];
  for (int i = idx; i < 512 * 1024; i += STR) cbuf[i] = b1[i & 1023];
  if (idx < BB * TT) {
    int b = idx >> 12, t = idx & (TT - 1);
    int r = -1;
    for (int s = 0; s < SS; ++s) {
      int st = bounds[(b * SS + s) * 2], en = bounds[(b * SS + s) * 2 + 1];
      if (t >= st && t < en) { r = s; break; }
    }
    sid[idx] = r;
  }
}

// ---------------- C += A @ B^T via atomics, K-split over blockIdx.z ----------------
__global__ __launch_bounds__(256) void gemm_bt_atomic(const float* __restrict__ A, int lda,
                                                      const float* __restrict__ Bm, int ldb,
                                                      float* __restrict__ C, int ldc,
                                                      int kper) {
  __shared__ u16 As[128 * 64];
  __shared__ u16 Bs[128 * 64];
  int tid = threadIdx.x;
  int m0 = blockIdx.x * 128, n0 = blockIdx.y * 128;
  int kbeg = blockIdx.z * kper;
  f32x4 acc[4][4] = {};

  for (int k0 = kbeg; k0 < kbeg + kper; k0 += 64) {
    __syncthreads();
    stage_tile(As, A + (size_t)m0 * lda + k0, lda, tid);
    stage_tile(Bs, Bm + (size_t)n0 * ldb + k0, ldb, tid);
    __syncthreads();
    int lane = tid & 63, wid = tid >> 6;
    int wm = wid >> 1, wn = wid & 1;
    int lr = lane & 15, lg = lane >> 4;
#pragma unroll
    for (int kk = 0; kk < 2; ++kk) {
      short8 af[4], bfr[4];
#pragma unroll
      for (int i = 0; i < 4; ++i) {
        int arow = wm * 64 + i * 16 + lr;
        int aslot = (kk * 4 + lg) ^ (arow & 7);
        af[i] = *(const short8*)(&As[(arow << 6) + (aslot << 3)]);
        int brow = wn * 64 + i * 16 + lr;
        int bslot = (kk * 4 + lg) ^ (brow & 7);
        bfr[i] = *(const short8*)(&Bs[(brow << 6) + (bslot << 3)]);
      }
#pragma unroll
      for (int i = 0; i < 4; ++i)
#pragma unroll
        for (int j = 0; j < 4; ++j)
          acc[i][j] = __builtin_amdgcn_mfma_f32_16x16x32_bf16(af[i], bfr[j], acc[i][j], 0, 0, 0);
    }
  }

  int lane = tid & 63, wid = tid >> 6;
  int wm = wid >> 1, wn = wid & 1;
  int lr = lane & 15, lg = lane >> 4;
#pragma unroll
  for (int i = 0; i < 4; ++i)
#pragma unroll
    for (int j = 0; j < 4; ++j)
#pragma unroll
      for (int r = 0; r < 4; ++r) {
        int row = m0 + wm * 64 + i * 16 + lg * 4 + r;
        int col = n0 + wn * 64 + j * 16 + lr;
        atomicAdd(&C[(size_t)row * ldc + col], acc[i][j][r]);
      }
}

// ---------------- K4: attention over S=64 per (b, head) ----------------
__global__ __launch_bounds__(256) void attn_kernel(const float* __restrict__ qkv,
                                                   float* __restrict__ ctx) {
  int bh = blockIdx.x;
  int b = bh >> 4, nh = bh & 15;
  __shared__ float q[64][64], k[64][64], v[64][64], s[64][64];
  int tid = threadIdx.x;
  const float* base = qkv + (size_t)b * SS * 3072 + nh * 64;
  for (int e = tid; e < 4096; e += 256) {
    int i = e >> 6, d = e & 63;
    q[i][d] = base[(size_t)i * 3072 + d];
    k[i][d] = base[(size_t)i * 3072 + 1024 + d];
    v[i][d] = base[(size_t)i * 3072 + 2048 + d];
  }
  __syncthreads();
  for (int e = tid; e < 4096; e += 256) {
    int i = e >> 6, j = e & 63;
    float acc = 0.f;
#pragma unroll 8
    for (int d = 0; d < 64; ++d) acc += q[i][d] * k[j][d];
    s[i][j] = acc * 0.125f;  // 1/sqrt(64)
  }
  __syncthreads();
  {
    int r = tid >> 2, sub = tid & 3;
    int j0 = sub * 16;
    float m = -1e30f;
#pragma unroll
    for (int j = 0; j < 16; ++j) m = fmaxf(m, s[r][j0 + j]);
    m = fmaxf(m, __shfl_xor(m, 1));
    m = fmaxf(m, __shfl_xor(m, 2));
    float sum = 0.f;
#pragma unroll
    for (int j = 0; j < 16; ++j) {
      float e_ = __expf(s[r][j0 + j] - m);
      s[r][j0 + j] = e_;
      sum += e_;
    }
    sum += __shfl_xor(sum, 1);
    sum += __shfl_xor(sum, 2);
    float inv = 1.0f / sum;
#pragma unroll
    for (int j = 0; j < 16; ++j) s[r][j0 + j] *= inv;
  }
  __syncthreads();
  for (int e = tid; e < 4096; e += 256) {
    int i = e >> 6, d = e & 63;
    float acc = 0.f;
#pragma unroll 8
    for (int j = 0; j < 64; ++j) acc += s[i][j] * v[j][d];
    ctx[((size_t)b * SS + i) * HH + nh * 64 + d] = acc;
  }
}

// ---------------- K7: partial score, 128x256 tile, 512 threads / 8 waves (2m x 4n) ----------------
// Round-8 proven sync structure (single-buffer, two __syncthreads per K-step,
// gload_lds staging, XCD-grouped mapping, no device fences). Geometry widened to
// N=256 per block: staged bytes drop 1.05GB -> 786MB (192 B/MFMA vs 256), B-tile
// spans two wbf row-tiles. 4 c-chunks per M-tile, consecutive on one XCD.
__global__ __launch_bounds__(512, 4) void score_partial(const u16* __restrict__ hbf,
                                                        const u16* __restrict__ wbf,
                                                        const float* __restrict__ cbuf,
                                                        const float* __restrict__ w2,
                                                        const int* __restrict__ sid_arr,
                                                        float* __restrict__ score_part) {
  __shared__ u16 As[8192];
  __shared__ u16 Bs[16384];
  __shared__ float w2_lds[256];
  __shared__ int sid_lds[128];
  __shared__ float red[128];

  int tid = threadIdx.x;
  int bid = blockIdx.x;
  int x = bid & 7;
  int g = bid >> 3;              // 0..127
  int mt = x * 32 + (g >> 2);    // 0..255
  int c = g & 3;                 // N-chunk of 256 cols
  int n0 = c * 256;
  size_t g0 = (size_t)mt * 128;  // global token row
  int b = (int)(g0 >> 12);       // / T
  const u16* asrc = hbf + (size_t)mt * 16 * 8192;

  if (tid < 256) w2_lds[tid] = w2[n0 + tid];
  if (tid < 128) {
    sid_lds[tid] = sid_arr[g0 + tid];
    red[tid] = 0.f;
  }

  int lane = tid & 63, wid = tid >> 6;  // wid 0..7
  int wm = wid >> 2, wn = wid & 3;      // 2 x 4 wave grid, each 64x64
  int lr = lane & 15, lg = lane >> 4;

  f32x4 acc[4][4] = {};
  for (int kt = 0; kt < 16; ++kt) {
    __syncthreads();  // previous iteration's LDS reads complete
    const u16* at = asrc + kt * 8192;
#pragma unroll
    for (int q = 0; q < 2; ++q) {
      int off = q * 4096 + wid * 512;   // wave-uniform u16 base
      GLOAD16(at + off + lane * 8, &As[off]);
    }
#pragma unroll
    for (int q = 0; q < 4; ++q) {
      int half = q >> 1;                // which 128-row half of the 256-row B tile
      int boff = (q & 1) * 4096 + wid * 512;
      const u16* bt = wbf + ((size_t)(2 * c + half) * 16 + kt) * 8192;
      GLOAD16(bt + boff + lane * 8, &Bs[half * 8192 + boff]);
    }
    __syncthreads();  // compiler drains vmcnt(0) before barrier -> tile ready
#pragma unroll
    for (int kk = 0; kk < 2; ++kk) {
      short8 af[4], bfr[4];
#pragma unroll
      for (int i = 0; i < 4; ++i) {
        int arow = wm * 64 + i * 16 + lr;
        int aslot = (kk * 4 + lg) ^ (arow & 7);
        af[i] = *(const short8*)(&As[(arow << 6) + (aslot << 3)]);
      }
#pragma unroll
      for (int j = 0; j < 4; ++j) {
        int brow = wn * 64 + j * 16 + lr;       // 0..255
        int half = (wn * 64 + j * 16) >> 7;     // uniform per (wn,j)
        int r = brow & 127;
        int bslot = (kk * 4 + lg) ^ (r & 7);
        bfr[j] = *(const short8*)(&Bs[(half << 13) + (r << 6) + (bslot << 3)]);
      }
#pragma unroll
      for (int i = 0; i < 4; ++i)
#pragma unroll
        for (int j = 0; j < 4; ++j)
          acc[i][j] = __builtin_amdgcn_mfma_f32_16x16x32_bf16(af[i], bfr[j], acc[i][j], 0, 0, 0);
    }
  }

  // score epilogue: sp = sum_j w2[j] * relu(u + c[sid, j]) over this wave's 64 cols
  float sp[4][4];
#pragma unroll
  for (int i = 0; i < 4; ++i) {
#pragma unroll
    for (int r = 0; r < 4; ++r) {
      int rowl = wm * 64 + i * 16 + lg * 4 + r;
      int s = sid_lds[rowl];
      int sc = s < 0 ? 0 : s;
      const float* crow = cbuf + ((size_t)b * SS + sc) * HH + n0;
      float accs = 0.f;
#pragma unroll
      for (int j = 0; j < 4; ++j) {
        int coll = wn * 64 + j * 16 + lr;
        float t = acc[i][j][r] + crow[coll];
        if (t > 0.f) accs += t * w2_lds[coll];
      }
      sp[i][r] = accs;
    }
  }

  // reduce across the 16 lanes of each lane-group
#pragma unroll
  for (int i = 0; i < 4; ++i)
#pragma unroll
    for (int r = 0; r < 4; ++r) {
      float v = sp[i][r];
      v += __shfl_xor(v, 1);
      v += __shfl_xor(v, 2);
      v += __shfl_xor(v, 4);
      v += __shfl_xor(v, 8);
      sp[i][r] = v;
    }
  if (lr == 0) {
#pragma unroll
    for (int i = 0; i < 4; ++i)
#pragma unroll
      for (int r = 0; r < 4; ++r)
        atomicAdd(&red[wm * 64 + i * 16 + lg * 4 + r], sp[i][r]);
  }
  __syncthreads();
  if (tid < 128) score_part[(size_t)c * (BB * TT) + g0 + tid] = red[tid];
}

// ---------------- K9: out = hbf * (1 + covered*(sum_c spart + b2)), bf16 source ----------------
__global__ __launch_bounds__(256) void scale_kernel(const u16* __restrict__ hbf,
                                                    const float* __restrict__ score_part,
                                                    const float* __restrict__ b2,
                                                    const int* __restrict__ sid_arr,
                                                    float* __restrict__ out) {
  __shared__ float fac[16];
  int tid = threadIdx.x;
  int r0 = blockIdx.x * 16;
  if (tid < 16) {
    int t = r0 + tid;
    float s = b2[0];
#pragma unroll
    for (int c = 0; c < 4; ++c) s += score_part[(size_t)c * (BB * TT) + t];
    fac[tid] = (sid_arr[t] >= 0) ? (1.0f + s) : 1.0f;
  }
  __syncthreads();
  // 16 rows * 128 ushortx8-groups = 2048 groups; 8 per thread
  for (int e = tid; e < 16 * 128; e += 256) {
    int row = e >> 7, grp = e & 127;
    int kt = grp >> 3, slot = grp & 7;
    int grow = r0 + row;
    int rt = grow >> 7, r = grow & 127;
    const u16* tile = hbf + ((size_t)rt * 16 + kt) * 8192;
    ushortx8 v = *(const ushortx8*)(&tile[(r << 6) + ((slot ^ (r & 7)) << 3)]);
    float f = fac[row];
    float4 o0, o1;
    o0.x = bf2f(v[0]) * f; o0.y = bf2f(v[1]) * f; o0.z = bf2f(v[2]) * f; o0.w = bf2f(v[3]) * f;
    o1.x = bf2f(v[4]) * f; o1.y = bf2f(v[5]) * f; o1.z = bf2f(v[6]) * f; o1.w = bf2f(v[7]) * f;
    float4* dst = (float4*)(out + (size_t)grow * HH + grp * 8);
    dst[0] = o0;
    dst[1] = o1;
  }
}

extern "C" void kernel_launch(void* const* d_in, const int* in_sizes, int n_in,
                              void* d_out, int out_size, void* d_ws, size_t ws_size,
                              hipStream_t stream) {
  const float* h        = (const float*)d_in[0];
  const int*   bounds   = (const int*)d_in[1];
  const float* in_proj_w = (const float*)d_in[2];
  const float* in_proj_b = (const float*)d_in[3];
  const float* out_w    = (const float*)d_in[4];
  const float* out_b    = (const float*)d_in[5];
  const float* w1       = (const float*)d_in[6];
  const float* b1       = (const float*)d_in[7];
  const float* w2       = (const float*)d_in[8];
  const float* b2       = (const float*)d_in[9];
  float* out = (float*)d_out;

  char* ws = (char*)d_ws;
  float* sent  = (float*)(ws);                        // 2 MB
  float* qkv   = (float*)(ws + (2ull << 20));         // 6 MB
  float* ctx   = (float*)(ws + (8ull << 20));         // 2 MB
  float* att   = (float*)(ws + (10ull << 20));        // 2 MB
  float* cbuf  = (float*)(ws + (12ull << 20));        // 2 MB
  int*   sid   = (int*)(ws + (14ull << 20));          // 128 KB
  float* spart = (float*)(ws + (15ull << 20));        // 512 KB (4 chunks)
  u16*   hbf   = (u16*)(ws + (16ull << 20));          // 64 MB
  u16*   wbf   = (u16*)(ws + (80ull << 20));          // 2 MB

  // pre-convert operands of the big GEMM to tiled/swizzled bf16
  conv_tile_kernel<<<256 * 16, 256, 0, stream>>>(h, HH, 16, hbf);
  conv_tile_kernel<<<8 * 16, 256, 0, stream>>>(w1, 2 * HH, 16, wbf);  // w1a: k<1024

  pool_bf_kernel<<<BB * SS, 256, 0, stream>>>(hbf, bounds, sent);
  setup_misc<<<2048, 256, 0, stream>>>(in_proj_b, out_b, b1, bounds, qkv, att, cbuf, sid);

  // qkv = sent @ in_proj_w^T + in_proj_b   (512 x 3072, K=1024), K-split x4 (round-8 proven)
  gemm_bt_atomic<<<dim3(4, 24, 4), 256, 0, stream>>>(sent, HH, in_proj_w, HH, qkv, 3 * HH, 256);
  attn_kernel<<<BB * NHH, 256, 0, stream>>>(qkv, ctx);
  // attended = ctx @ out_w^T + out_b       (512 x 1024, K=1024), K-split x4
  gemm_bt_atomic<<<dim3(4, 8, 4), 256, 0, stream>>>(ctx, HH, out_w, HH, att, HH, 256);
  // c = attended @ w1b^T + b1              (512 x 1024, K=1024), w1b = w1[:, H:]
  gemm_bt_atomic<<<dim3(4, 8, 4), 256, 0, stream>>>(att, HH, w1 + HH, 2 * HH, cbuf, HH, 256);

  // big GEMM partial scores: 1024 blocks (256 M-tiles x 4 N-chunks), XCD-grouped
  score_partial<<<1024, 512, 0, stream>>>(hbf, wbf, cbuf, w2, sid, spart);
  scale_kernel<<<2048, 256, 0, stream>>>(hbf, spart, b2, sid, out);
}